// Round 12
// baseline (368.606 us; speedup 1.0000x reference)
//
#include <hip/hip_runtime.h>

// ---- problem constants ----
#define TT   512
#define BI   12
#define HH   50
#define BB   8     // batch per block
#define BTOT 2048
#define LOG2E 1.4426950408889634f

// R21 = R17 RESTORED (295.5us dispatch -- measured optimum: R18/R19/R20
// occupancy & density variants all regressed; recurrence needs >=3
// waves/SIMD of uncorrelated work, and every parallelism source costs
// more than it recovers) + ONE delta: L1 MFMA chain split 4-deep ->
// 2x 2-deep + f4 add. R17's regime is 66% busy (34% idle = latency
// exposed), unlike R12's 75% where the split was correctly reverted;
// removing ~2 dependent MFMA latencies (~50cy) from the serial floor
// (ds_read -> chain -> dppmerge -> act -> write) costs only 4 v_add_f32.
// Structure (R17, verified): ONE WAVE = ONE M-TILE = BOTH LAYERS.
//  - wave w (0..12) owns tile w for L0 AND L1: bf0/bf1 = B0s[P]
//    (h0(t-1)+x(t)+bias; shared by both layers -- L1's A zeroes cols
//    50-63), bf2/bf3 = B1s[P] (h1(t-2)+bias); acc0 = L0 2-chain,
//    acc1 = L1 2+2-chain.
//  - dppmerge merges LAYERS: slot0 lanes (n16<8) keep acc0 -> L0 cell
//    (u_m,bcol); slot1 lanes take acc1 from lane^8 -> L1 cell. One act
//    bundle per wave serves both layers; writes to B0s/B1s at row u_m.
//  - x-duty on waves 13-15 lanes 0-31 (96 = BB*BI slots); setprio(1) on
//    compute waves; one barrier/step; parity: reads [P], writes [1-P];
//    pipeline l0->h0[t], l1->h1[t-1]; 2-ahead xhold prefetch.
// Carried: trans fusion (5 exp2 + 2 rcp, common-denominator cell update,
// exp2-arg clamp 60), scales folded into f16 weights, fzero C-operand,
// B0s=[h0 0-49|x 50-61|bias 62], B1s=[h1 0-49|bias 62], LDS 8KB.

typedef _Float16 half8 __attribute__((ext_vector_type(8)));
typedef float    f4    __attribute__((ext_vector_type(4)));

__device__ __forceinline__ float sigm_(float v) {
    return __builtin_amdgcn_rcpf(1.f + __builtin_amdgcn_exp2f(v * (-LOG2E)));
}
// lanes with (lane&15)<8 keep a0; lanes with (lane&15)>=8 take a1 from
// lane^8 (DPP row_ror:8 = 0x128, banks 2,3 -> bank_mask 0xC). One VALU op.
__device__ __forceinline__ float dppmerge_(float a0, float a1) {
    int r = __builtin_amdgcn_update_dpp(__builtin_bit_cast(int, a0),
                                        __builtin_bit_cast(int, a1),
                                        0x128, 0xF, 0xC, false);
    return __builtin_bit_cast(float, r);
}

__launch_bounds__(1024)
__global__ void lstm2_kernel(const float* __restrict__ x,
                             const float* __restrict__ w_ih0, const float* __restrict__ w_hh0,
                             const float* __restrict__ b_ih0, const float* __restrict__ b_hh0,
                             const float* __restrict__ w_ih1, const float* __restrict__ w_hh1,
                             const float* __restrict__ b_ih1, const float* __restrict__ b_hh1,
                             const float* __restrict__ w_out, const float* __restrict__ b_out,
                             float* __restrict__ out)
{
    const int tid   = threadIdx.x;
    const int wv    = tid >> 6;          // 0..15
    const int lane  = tid & 63;
    const int b0    = blockIdx.x * BB;

    const int m    = lane & 15;
    const int q    = lane >> 4;          // 0..3
    const int slot = m >> 3;             // 0: L0 role, 1: L1 role
    const int bcol = m & 7;
    const int T    = wv;                 // M-tile (compute waves only)
    const bool comp = (wv < 13);
    const int u_m  = T * 4 + q;          // unit owned by this lane
    const bool wvalid = comp && (u_m < HH);

    if (comp) __builtin_amdgcn_s_setprio(1);

    // K-space: B0s rows = [h0: 0-49 | x: 50-61 | bias(=1): 62 | pad: 63]
    //          B1s rows = [h1: 0-49 | unused: 50-61 | bias(=1): 62 | pad: 63]
    __shared__ __align__(16) _Float16 B0s[2][64 * 16];
    __shared__ __align__(16) _Float16 B1s[2][64 * 16];

    // ---- step-invariant A fragments (pre-scaled), tile T, both layers ----
    const int uA = T * 4 + (m >> 2);     // A-fragment row unit
    const int gA = m & 3;                // gate
    half8 af0[2], af1[4];
    #pragma unroll
    for (int kb = 0; kb < 2; kb++) {
        #pragma unroll
        for (int j = 0; j < 8; j++) {
            float v = 0.f;
            if (comp && uA < HH) {
                const int r  = gA * HH + uA;
                const int kg = kb * 32 + q * 8 + j;
                if      (kg < 50)  v = w_hh0[r * HH + kg];
                else if (kg < 62)  v = w_ih0[r * BI + (kg - 50)];
                else if (kg == 62) v = b_ih0[r] + b_hh0[r];
                v *= (gA == 2) ? (2.f * LOG2E) : (-LOG2E);
            }
            af0[kb][j] = (_Float16)v;
        }
    }
    #pragma unroll
    for (int kb = 0; kb < 4; kb++) {
        #pragma unroll
        for (int j = 0; j < 8; j++) {
            float v = 0.f;
            if (comp && uA < HH) {
                const int r  = gA * HH + uA;
                const int kg = kb * 32 + q * 8 + j;
                if      (kg < 50)               v = w_ih1[r * HH + kg];
                else if (kg >= 64 && kg < 114)  v = w_hh1[r * HH + (kg - 64)];
                else if (kg == 126)             v = b_ih1[r] + b_hh1[r];
                v *= (gA == 2) ? (2.f * LOG2E) : (-LOG2E);
            }
            af1[kb][j] = (_Float16)v;
        }
    }

    // ---- init LDS ----
    for (int i = tid; i < 2 * 64 * 16; i += 1024) {
        (&B0s[0][0])[i] = (_Float16)0.f;
        (&B1s[0][0])[i] = (_Float16)0.f;
    }
    __syncthreads();
    if (tid < 16) {                       // bias (ones) row 62, both parities
        B0s[0][7 * 128 + tid * 8 + 6] = (_Float16)1.f;
        B0s[1][7 * 128 + tid * 8 + 6] = (_Float16)1.f;
        B1s[0][7 * 128 + tid * 8 + 6] = (_Float16)1.f;
        B1s[1][7 * 128 + tid * 8 + 6] = (_Float16)1.f;
    }

    // ---- x-duty: waves 13-15, lanes 0-31 -> 96 slots = BB*BI ----
    const bool xact = (wv >= 13) && (lane < 32);
    const int xidx  = (wv - 13) * 32 + lane;               // 0..95 on xact
    const int xb    = xidx / 12, xi = xidx - xb * 12;
    const int xrow  = 50 + xi;
    const int xoff  = (xrow >> 3) * 128 + xb * 8 + (xrow & 7);
    const size_t xbase = ((size_t)(b0 + xb) * TT) * BI + xi;
    if (xact)                              // x[0] -> parity 0
        B0s[0][xoff] = (_Float16)x[xbase];
    __syncthreads();

    // ---- per-parity pointers (loop-invariant) ----
    const _Float16* rd0[2] = { &B0s[0][0] + lane * 8, &B0s[1][0] + lane * 8 };
    const _Float16* rd1[2] = { &B1s[0][0] + lane * 8, &B1s[1][0] + lane * 8 };
    const int offA = (u_m >> 3) * 128 + bcol * 8 + (u_m & 7);   // h row = u_m
    _Float16* wAp[2] = { (slot ? &B1s[0][0] : &B0s[0][0]) + offA,
                         (slot ? &B1s[1][0] : &B0s[1][0]) + offA };
    _Float16* xdp[2] = { &B0s[0][0] + xoff, &B0s[1][0] + xoff };

    const f4 fzero = {0.f, 0.f, 0.f, 0.f};
    float cm = 0.f;                        // cell state for (slot-layer, u_m, bcol)

    // x stream, 2-step-ahead: xhold carries x[t+1] across a full step.
    const float* xq = x + xbase + BI;     // points at x[1]
    float xhold = 0.f;
    if (xact) xhold = *xq;                // preload x[1]
    xq += BI;                             // points at x[2]

// One timestep at compile-time parity P (flags/parity as R16/R17).
// Per-lane activity: slot0 lanes live iff DOL0, slot1 iff DOL1 (folds to
// true in the main loop). MFMAs run unconditionally on compute waves
// (stale operands in peel steps are discarded by the predicate).
#define STEP(P, DOL0, DOL1, DOST, DOLD)                                       \
  {                                                                           \
    float xnew = 0.f;                                                         \
    if ((DOLD) && xact) xnew = *xq;                                           \
    if ((DOST) && xact) *xdp[1 - (P)] = (_Float16)xhold;                      \
    if (comp) {                                                               \
      const half8 bf0 = *(const half8*)(rd0[P]);                              \
      const half8 bf1 = *(const half8*)(rd0[P] + 512);                        \
      const half8 bf2 = *(const half8*)(rd1[P]);                              \
      const half8 bf3 = *(const half8*)(rd1[P] + 512);                        \
      f4 acc0, acc1;                                                          \
      acc0 = __builtin_amdgcn_mfma_f32_16x16x32_f16(af0[0], bf0, fzero, 0, 0, 0); \
      acc0 = __builtin_amdgcn_mfma_f32_16x16x32_f16(af0[1], bf1, acc0, 0, 0, 0);  \
      {                                                                       \
        f4 p1 = __builtin_amdgcn_mfma_f32_16x16x32_f16(af1[0], bf0, fzero, 0, 0, 0); \
        f4 p2 = __builtin_amdgcn_mfma_f32_16x16x32_f16(af1[1], bf1, fzero, 0, 0, 0); \
        p1 = __builtin_amdgcn_mfma_f32_16x16x32_f16(af1[2], bf2, p1, 0, 0, 0);       \
        p2 = __builtin_amdgcn_mfma_f32_16x16x32_f16(af1[3], bf3, p2, 0, 0, 0);       \
        acc1 = p1 + p2;                                                       \
      }                                                                       \
      f4 am;                                                                  \
      _Pragma("unroll")                                                       \
      for (int i = 0; i < 4; i++) am[i] = dppmerge_(acc0[i], acc1[i]);        \
      const float eI = __builtin_amdgcn_exp2f(am[0]);                         \
      const float eF = __builtin_amdgcn_exp2f(am[1]);                         \
      const float eG = __builtin_amdgcn_exp2f(am[2]);                         \
      const float eO = __builtin_amdgcn_exp2f(am[3]);                         \
      const float dI = 1.f + eI, dF = 1.f + eF;                               \
      const float dG = 1.f + eG, dO = 1.f + eO;                               \
      const float pIG = dI * dG;                                              \
      const float num = __builtin_fmaf(cm, pIG, (eG - 1.f) * dF);             \
      const float cmn = num * __builtin_amdgcn_rcpf(dF * pIG);                \
      const float uu  = fminf(cmn * (2.f * LOG2E), 60.f);                     \
      const float eC  = __builtin_amdgcn_exp2f(uu);                           \
      const float h   = (eC - 1.f) * __builtin_amdgcn_rcpf(dO * (1.f + eC));  \
      const bool actp = slot ? (bool)(DOL1) : (bool)(DOL0);                   \
      if (actp) cm = cmn;                                                     \
      if (actp && wvalid) *wAp[1 - (P)] = (_Float16)h;                        \
    }                                                                         \
    if (DOLD) { xhold = xnew; xq += BI; }                                     \
    __syncthreads();                                                          \
  }

    STEP(0, 1, 0, 1, 1)                   // t = 0   (l0 only; store x[1], load x[2])
    STEP(1, 1, 1, 1, 1)                   // t = 1
    #pragma unroll 1
    for (int it = 0; it < 254; ++it) {    // t = 2 .. 509
        STEP(0, 1, 1, 1, 1)
        STEP(1, 1, 1, 1, 1)
    }
    STEP(0, 1, 1, 1, 0)                   // t = 510 (store x[511], no more loads)
    STEP(1, 1, 1, 0, 0)                   // t = 511
    STEP(0, 0, 1, 0, 0)                   // t = 512 (l1 drain: h1[511] -> B1s[1])
#undef STEP

    // ---- epilogue: sigmoid(h1[TT-1] . w_out + b_out); h1[511] in B1s[1] ----
    if (tid < BB) {
        float s = b_out[0];
        #pragma unroll
        for (int u = 0; u < HH; u++) {
            s += w_out[u] * (float)B1s[1][(u >> 3) * 128 + tid * 8 + (u & 7)];
        }
        out[b0 + tid] = sigm_(s);
    }
}

extern "C" void kernel_launch(void* const* d_in, const int* in_sizes, int n_in,
                              void* d_out, int out_size, void* d_ws, size_t ws_size,
                              hipStream_t stream) {
    const float* x     = (const float*)d_in[0];
    const float* w_ih0 = (const float*)d_in[1];
    const float* w_hh0 = (const float*)d_in[2];
    const float* b_ih0 = (const float*)d_in[3];
    const float* b_hh0 = (const float*)d_in[4];
    const float* w_ih1 = (const float*)d_in[5];
    const float* w_hh1 = (const float*)d_in[6];
    const float* b_ih1 = (const float*)d_in[7];
    const float* b_hh1 = (const float*)d_in[8];
    const float* w_out = (const float*)d_in[9];
    const float* b_out = (const float*)d_in[10];
    float* out = (float*)d_out;

    dim3 grid(BTOT / BB);   // 256 blocks -> 1 per CU
    dim3 block(1024);       // 13 merged-layer compute waves + 3 x-waves
    lstm2_kernel<<<grid, block, 0, stream>>>(x, w_ih0, w_hh0, b_ih0, b_hh0,
                                             w_ih1, w_hh1, b_ih1, b_hh1,
                                             w_out, b_out, out);
}